// Round 10
// baseline (871.907 us; speedup 1.0000x reference)
//
#include <hip/hip_runtime.h>
#include <hip/hip_cooperative_groups.h>
#include <stdint.h>

namespace cg = cooperative_groups;

#define NN 8192
#define MM 16
#define FN 128
#define HH 512

typedef unsigned short u16;
typedef unsigned int u32;
typedef __bf16 bf16;
typedef __bf16 bf16x8 __attribute__((ext_vector_type(8)));
typedef float f32x4 __attribute__((ext_vector_type(4)));

// async global->LDS, 16B/lane; LDS dest = wave-uniform base + lane*16
__device__ __forceinline__ void gld_lds16(const u16* g, u16* l) {
  __builtin_amdgcn_global_load_lds(
      (const __attribute__((address_space(1))) void*)g,
      (__attribute__((address_space(3))) void*)l, 16, 0, 0);
}

// ---- dtype probes (per-wave; ~2 cached loads + ballot) ----
__device__ __forceinline__ int probe_f32(const u16* w) {
  int lane = threadIdx.x & 63;
  int e = (w[2 * lane] >> 7) & 0xFF;
  unsigned long long m = __ballot(!(e == 0 || (e >= 90 && e <= 140)));
  return __popcll(m) >= 8;
}
__device__ __forceinline__ int probe_i64(const u32* w) {
  int lane = threadIdx.x & 63;
  unsigned long long m = __ballot(lane < 32 && w[2 * lane + 1] != 0);
  return m == 0;
}
__device__ __forceinline__ bf16 cvt_elem(const void* p, size_t i, int f32) {
  return f32 ? (bf16)((const float*)p)[i] : ((const bf16*)p)[i];
}

// ---- phase: transpose one 32x32 tile of W (512x512) -> T (512x512), 512 thr
__device__ __forceinline__ void phase_transpose(const void* __restrict__ W,
                                                u16* __restrict__ T, int tt,
                                                int f32in, u16* sm) {
  const int k0 = (tt >> 4) * 32, n0 = (tt & 15) * 32;
  const int tx = threadIdx.x & 31, ty = threadIdx.x >> 5;  // ty 0..15
#pragma unroll
  for (int r = ty; r < 32; r += 16) {
    bf16 v = cvt_elem(W, (size_t)(k0 + r) * HH + n0 + tx, f32in);
    sm[r * 33 + tx] = *(u16*)&v;
  }
  __syncthreads();
#pragma unroll
  for (int r = ty; r < 32; r += 16)
    T[(size_t)(n0 + r) * HH + k0 + tx] = sm[tx * 33 + r];
}

// ---- phase: deg  (vb in 0..15; 512 nodes each)
__device__ __forceinline__ void phase_deg(int vb, const u32* __restrict__ idxw,
                                          int i64, float* __restrict__ dis) {
  const int i = vb * 512 + threadIdx.x;
  const int* idx = (const int*)idxw;
  int c = 1;
#pragma unroll
  for (int e = 0; e < MM; ++e) c += (idx[(i * MM + e) << i64] >= 0) ? 1 : 0;
  dis[i] = rsqrtf((float)c);
}

// ---- phase: TWc = (Wemb@W1)^T directly from raw inputs (vb in 0..7).
// Tile 64 (Wemb rows) x 128 (W1 cols), K=512, BK=64. B staged via in-LDS
// transpose of raw W1 rows; C written transposed into TWc (512 x 128).
__device__ void phase_wc(int vb, const void* __restrict__ Wemb,
                         const void* __restrict__ W1, int f32in,
                         u16* __restrict__ TWc, u16* As, u16* Bs) {
  const int tid = threadIdx.x;
  const int rtile = vb >> 2, ctile = vb & 3;
  const int wave = tid >> 6, lane = tid & 63;
  const int wr = wave >> 2, wcq = wave & 3;
  const int quad = lane >> 4, l16 = lane & 15;
  f32x4 acc[2][2] = {};
  const int arow = tid >> 3, agc = (tid & 7) ^ ((tid >> 3) & 7);
  for (int k0 = 0; k0 < HH; k0 += 64) {
    __syncthreads();
    {  // A: Wemb[(rtile*64+arow)][k0 + agc*8 .. +8] -> linear chunk tid
      size_t src = (size_t)(rtile * 64 + arow) * HH + k0 + agc * 8;
      bf16x8 av;
      if (f32in) {
        const float* pp = (const float*)Wemb + src;
        f32x4 x0 = *(const f32x4*)pp, x1 = *(const f32x4*)(pp + 4);
#pragma unroll
        for (int t = 0; t < 4; ++t) { av[t] = (bf16)x0[t]; av[4 + t] = (bf16)x1[t]; }
      } else {
        av = *(const bf16x8*)((const u16*)Wemb + src);
      }
      *(bf16x8*)&As[tid * 8] = av;
    }
#pragma unroll
    for (int i = 0; i < 2; ++i) {  // B: W1 rows -> transposed swizzled LDS
      int t2 = i * 512 + tid;
      int kk = t2 >> 4, seg = (t2 & 15) * 8;
      size_t src = (size_t)(k0 + kk) * HH + ctile * 128 + seg;
      bf16 e8[8];
      if (f32in) {
        const float* pp = (const float*)W1 + src;
        f32x4 x0 = *(const f32x4*)pp, x1 = *(const f32x4*)(pp + 4);
#pragma unroll
        for (int t = 0; t < 4; ++t) { e8[t] = (bf16)x0[t]; e8[4 + t] = (bf16)x1[t]; }
      } else {
        bf16x8 v = *(const bf16x8*)((const u16*)W1 + src);
#pragma unroll
        for (int t = 0; t < 8; ++t) e8[t] = v[t];
      }
#pragma unroll
      for (int j = 0; j < 8; ++j) {
        int n = seg + j;
        int cc = (kk >> 3) ^ j;  // j == n&7
        Bs[n * 64 + cc * 8 + (kk & 7)] = *(u16*)&e8[j];
      }
    }
    __syncthreads();
#pragma unroll
    for (int h = 0; h < 2; ++h) {
      bf16x8 af[2], bfr[2];
#pragma unroll
      for (int i = 0; i < 2; ++i) {
        int r = wr * 32 + i * 16 + l16;
        int cc = (h * 4 + quad) ^ (r & 7);
        af[i] = *(const bf16x8*)&As[r * 64 + cc * 8];
      }
#pragma unroll
      for (int j = 0; j < 2; ++j) {
        int n = wcq * 32 + j * 16 + l16;
        int cc = (h * 4 + quad) ^ (n & 7);
        bfr[j] = *(const bf16x8*)&Bs[n * 64 + cc * 8];
      }
#pragma unroll
      for (int i = 0; i < 2; ++i)
#pragma unroll
        for (int j = 0; j < 2; ++j)
          acc[i][j] = __builtin_amdgcn_mfma_f32_16x16x32_bf16(af[i], bfr[j],
                                                              acc[i][j], 0, 0, 0);
    }
  }
  const int crow0 = rtile * 64 + wr * 32 + quad * 4;
  const int ccol0 = ctile * 128 + wcq * 32 + l16;
#pragma unroll
  for (int j = 0; j < 2; ++j)
#pragma unroll
    for (int i = 0; i < 2; ++i)
#pragma unroll
      for (int r = 0; r < 4; ++r) {
        bf16 o = (bf16)acc[i][j][r];
        TWc[(size_t)(ccol0 + j * 16) * FN + crow0 + i * 16 + r] = *(u16*)&o;
      }
}

// ---- phase: bvec[n] = sum_m bemb[m]*W1[m][n]  (one block, coalesced cols)
__device__ void phase_bvec(const void* __restrict__ bemb,
                           const void* __restrict__ W1, int f32in,
                           float* __restrict__ bvec, float* bembS) {
  const int tid = threadIdx.x;
  bembS[tid] = (float)cvt_elem(bemb, tid, f32in);
  __syncthreads();
  float acc = 0.f;
#pragma unroll 8
  for (int m = 0; m < HH; ++m)
    acc += bembS[m] * (float)cvt_elem(W1, (size_t)m * HH + tid, f32in);
  bvec[tid] = acc;
}

// ---- phase: GEMM tile C[rt*64..+64][ct*128..+128] = A@Bt^T (+biasf)
// 512 thr / 8 waves (2x4), wave 32x32 (2x2 accs 16x16x32), BK=64,
// gld_lds + XOR swizzle (proven R5-R9: correct, 0 bank conflicts).
__device__ void phase_gemm(int vb, const void* __restrict__ A, int K, int af32,
                           const u16* __restrict__ Bt,
                           const float* __restrict__ biasf, u16* __restrict__ C,
                           u16* As, u16* Bs) {
  const int tid = threadIdx.x;
  const int rtile = vb >> 2, ctile = vb & 3;
  const int wave = tid >> 6, lane = tid & 63;
  const int wr = wave >> 2, wcq = wave & 3;
  const int quad = lane >> 4, l16 = lane & 15;
  f32x4 acc[2][2] = {};
  const int arow = tid >> 3, agc = (tid & 7) ^ ((tid >> 3) & 7);
  int brow[2], bgc[2];
#pragma unroll
  for (int i = 0; i < 2; ++i) {
    int c = i * 512 + tid;
    brow[i] = c >> 3;
    bgc[i] = (c & 7) ^ (brow[i] & 7);
  }
  u16* AsW = As + wave * 512;
  u16* BsW0 = Bs + wave * 512;
  u16* BsW1 = Bs + 4096 + wave * 512;
  for (int k0 = 0; k0 < K; k0 += 64) {
    __syncthreads();
    if (af32) {
      const float* pp = (const float*)A + (size_t)(rtile * 64 + arow) * K + k0 + agc * 8;
      f32x4 x0 = *(const f32x4*)pp, x1 = *(const f32x4*)(pp + 4);
      bf16x8 av;
#pragma unroll
      for (int t = 0; t < 4; ++t) { av[t] = (bf16)x0[t]; av[4 + t] = (bf16)x1[t]; }
      *(bf16x8*)&As[tid * 8] = av;
    } else {
      gld_lds16((const u16*)A + (size_t)(rtile * 64 + arow) * K + k0 + agc * 8, AsW);
    }
    gld_lds16(Bt + (size_t)(ctile * 128 + brow[0]) * K + k0 + bgc[0] * 8, BsW0);
    gld_lds16(Bt + (size_t)(ctile * 128 + brow[1]) * K + k0 + bgc[1] * 8, BsW1);
    __syncthreads();
#pragma unroll
    for (int h = 0; h < 2; ++h) {
      bf16x8 af[2], bfr[2];
#pragma unroll
      for (int i = 0; i < 2; ++i) {
        int r = wr * 32 + i * 16 + l16;
        int cc = (h * 4 + quad) ^ (r & 7);
        af[i] = *(const bf16x8*)&As[r * 64 + cc * 8];
      }
#pragma unroll
      for (int j = 0; j < 2; ++j) {
        int n = wcq * 32 + j * 16 + l16;
        int cc = (h * 4 + quad) ^ (n & 7);
        bfr[j] = *(const bf16x8*)&Bs[n * 64 + cc * 8];
      }
#pragma unroll
      for (int i = 0; i < 2; ++i)
#pragma unroll
        for (int j = 0; j < 2; ++j)
          acc[i][j] = __builtin_amdgcn_mfma_f32_16x16x32_bf16(af[i], bfr[j],
                                                              acc[i][j], 0, 0, 0);
    }
  }
  const int crow0 = rtile * 64 + wr * 32 + quad * 4;
  const int ccol0 = ctile * 128 + wcq * 32 + l16;
#pragma unroll
  for (int j = 0; j < 2; ++j) {
    const int col = ccol0 + j * 16;
    const float bv = biasf ? biasf[col] : 0.f;
#pragma unroll
    for (int i = 0; i < 2; ++i)
#pragma unroll
      for (int r = 0; r < 4; ++r) {
        bf16 o = (bf16)(acc[i][j][r] + bv);
        C[(size_t)(crow0 + i * 16 + r) * HH + col] = *(u16*)&o;
      }
  }
}

// ---- phase: agg + epilogue, XCD-strip mapping (vb in 0..1023; 32 units/blk)
__device__ void phase_agg(int vb, const u16* __restrict__ t,
                          const u32* __restrict__ idxw, int i64,
                          const float* __restrict__ dis,
                          const void* __restrict__ bias, int f32io, bool relu,
                          bool fin, void* __restrict__ y) {
  const int* idx = (const int*)idxw;
  const int s = (vb & 7) >> 1;
  const int w = (vb >> 3) * 2 + (vb & 1);
  const int tid = threadIdx.x;
  const int node = w * 32 + (tid >> 4);
  const int c0 = s * 128 + (tid & 15) * 8;
  const float wi = dis[node];
  float acc[8];
  bf16x8 xs = *(const bf16x8*)&t[(size_t)node * HH + c0];
#pragma unroll
  for (int k = 0; k < 8; ++k) acc[k] = wi * wi * (float)xs[k];
#pragma unroll
  for (int e = 0; e < MM; ++e) {
    const int j = idx[(node * MM + e) << i64];
    if (j >= 0) {
      const float ww = wi * dis[j];
      bf16x8 v = *(const bf16x8*)&t[(size_t)j * HH + c0];
#pragma unroll
      for (int k = 0; k < 8; ++k) acc[k] += ww * (float)v[k];
    }
  }
  float bv[8];
  if (f32io) {
    f32x4 b0 = *(const f32x4*)&((const float*)bias)[c0];
    f32x4 b1 = *(const f32x4*)&((const float*)bias)[c0 + 4];
#pragma unroll
    for (int k = 0; k < 4; ++k) { bv[k] = b0[k]; bv[4 + k] = b1[k]; }
  } else {
    bf16x8 bb = *(const bf16x8*)&((const u16*)bias)[c0];
#pragma unroll
    for (int k = 0; k < 8; ++k) bv[k] = (float)bb[k];
  }
#pragma unroll
  for (int k = 0; k < 8; ++k) {
    acc[k] += bv[k];
    if (relu) acc[k] = fmaxf(acc[k], 0.f);
  }
  if (fin && f32io) {
    float* O = (float*)y;
    f32x4 o0, o1;
#pragma unroll
    for (int k = 0; k < 4; ++k) { o0[k] = acc[k]; o1[k] = acc[4 + k]; }
    *(f32x4*)&O[(size_t)node * HH + c0] = o0;
    *(f32x4*)&O[(size_t)node * HH + c0 + 4] = o1;
  } else {
    bf16x8 o;
#pragma unroll
    for (int k = 0; k < 8; ++k) o[k] = (bf16)acc[k];
    *(bf16x8*)&((u16*)y)[(size_t)node * HH + c0] = o;
  }
}

// ---- cooperative mega: 768 blocks x 512 thr (3 blk/CU), 6 grid.syncs ----
__global__ __launch_bounds__(512, 6) void mega(
    const u16* __restrict__ node, const u32* __restrict__ idxw,
    const void* __restrict__ Wemb, const void* __restrict__ bemb,
    const void* __restrict__ W1, const void* __restrict__ b1,
    const void* __restrict__ W2, const void* __restrict__ b2,
    const void* __restrict__ W3, const void* __restrict__ b3,
    void* __restrict__ out, float* __restrict__ dis, float* __restrict__ bvec,
    u16* __restrict__ TWc, u16* __restrict__ TW2, u16* __restrict__ TW3,
    u16* __restrict__ xA) {
  __shared__ __align__(16) u16 smem[12288];  // 24 KB: As 8K + Bs 16K (unioned)
  u16* As = smem;
  u16* Bs = smem + 4096;
  cg::grid_group grid = cg::this_grid();
  const int bid = blockIdx.x;
  const int f32in = probe_f32(node);
  const int i64 = probe_i64(idxw);
  u16* xO = (u16*)out;  // d_out doubles as bf16 ping buffer

  // P0: TW2 transposes (0..255) + deg (256..271) + TWc (272..279) + bvec (280)
  if (bid < 256) phase_transpose(W2, TW2, bid, f32in, smem);
  else if (bid < 272) phase_deg(bid - 256, idxw, i64, dis);
  else if (bid < 280) phase_wc(bid - 272, Wemb, W1, f32in, TWc, As, Bs);
  else if (bid == 280) phase_bvec(bemb, W1, f32in, bvec, (float*)smem);
  grid.sync();
  // P1: g1 = node@TWc^T + bvec (0..511) + TW3 transposes (512..767)
  if (bid < 512) phase_gemm(bid, node, FN, f32in, TWc, bvec, xA, As, Bs);
  else phase_transpose(W3, TW3, bid - 512, f32in, smem);
  grid.sync();
  for (int vb = bid; vb < 1024; vb += 768)  // P2: a1 (+b1, relu)
    phase_agg(vb, xA, idxw, i64, dis, b1, f32in, true, false, xO);
  grid.sync();
  if (bid < 512) phase_gemm(bid, xO, HH, 0, TW2, nullptr, xA, As, Bs);  // P3
  grid.sync();
  for (int vb = bid; vb < 1024; vb += 768)  // P4: a2 (+b2, relu)
    phase_agg(vb, xA, idxw, i64, dis, b2, f32in, true, false, xO);
  grid.sync();
  if (bid < 512) phase_gemm(bid, xO, HH, 0, TW3, nullptr, xA, As, Bs);  // P5
  grid.sync();
  for (int vb = bid; vb < 1024; vb += 768)  // P6: a3 (+b3, final dtype)
    phase_agg(vb, xA, idxw, i64, dis, b3, f32in, false, true, out);
}

// ---- fallback (if cooperative launch is rejected): same phases, 7 launches
__global__ __launch_bounds__(512) void fb_p0(
    const u16* node, const u32* idxw, const void* Wemb, const void* bemb,
    const void* W1, const void* W2, float* dis, float* bvec, u16* TWc,
    u16* TW2) {
  __shared__ __align__(16) u16 smem[12288];
  const int bid = blockIdx.x;
  const int f32in = probe_f32(node);
  const int i64 = probe_i64(idxw);
  if (bid < 256) phase_transpose(W2, TW2, bid, f32in, smem);
  else if (bid < 272) phase_deg(bid - 256, idxw, i64, dis);
  else if (bid < 280) phase_wc(bid - 272, Wemb, W1, f32in, TWc, smem, smem + 4096);
  else phase_bvec(bemb, W1, f32in, bvec, (float*)smem);
}
__global__ __launch_bounds__(512) void fb_p1(const u16* node, const void* W3,
                                             const u16* TWc, const float* bvec,
                                             u16* TW3, u16* xA) {
  __shared__ __align__(16) u16 smem[12288];
  const int bid = blockIdx.x;
  const int f32in = probe_f32(node);
  if (bid < 512) phase_gemm(bid, node, FN, f32in, TWc, bvec, xA, smem, smem + 4096);
  else phase_transpose(W3, TW3, bid - 512, f32in, smem);
}
__global__ __launch_bounds__(512) void fb_gemm(const u16* A, const u16* Bt,
                                               u16* C) {
  __shared__ __align__(16) u16 smem[12288];
  phase_gemm(blockIdx.x, A, HH, 0, Bt, nullptr, C, smem, smem + 4096);
}
template <bool RELU, bool FIN>
__global__ __launch_bounds__(512) void fb_agg(const u16* t, const u32* idxw,
                                              const float* dis, const void* bias,
                                              const u16* nodeprobe, void* y) {
  const int f32io = probe_f32(nodeprobe);
  const int i64 = probe_i64(idxw);
  phase_agg(blockIdx.x, t, idxw, i64, dis, bias, f32io, RELU, FIN, y);
}

extern "C" void kernel_launch(void* const* d_in, const int* in_sizes, int n_in,
                              void* d_out, int out_size, void* d_ws, size_t ws_size,
                              hipStream_t stream) {
  const u16* node = (const u16*)d_in[0];
  const u32* idxw = (const u32*)d_in[1];
  const void* Wemb = d_in[2];
  const void* bemb = d_in[3];
  const void* W1 = d_in[4];
  const void* b1 = d_in[5];
  const void* W2 = d_in[6];
  const void* b2 = d_in[7];
  const void* W3 = d_in[8];
  const void* b3 = d_in[9];
  void* out = d_out;

  char* p = (char*)d_ws;
  float* dis = (float*)p;   p += NN * sizeof(float);
  float* bvec = (float*)p;  p += HH * sizeof(float);
  u16* TWc = (u16*)p;       p += (size_t)HH * FN * 2;
  u16* TW2 = (u16*)p;       p += (size_t)HH * HH * 2;
  u16* TW3 = (u16*)p;       p += (size_t)HH * HH * 2;
  u16* xA = (u16*)p;        // 8 MB GEMM-out buffer
  u16* xO = (u16*)d_out;    // bf16 ping buffer

  void* kargs[] = {&node, &idxw, &Wemb, &bemb, &W1, &b1, &W2, &b2, &W3,
                   &b3,   &out,  &dis,  &bvec, &TWc, &TW2, &TW3, &xA};
  hipError_t e = hipLaunchCooperativeKernel((void*)mega, dim3(768), dim3(512),
                                            kargs, 0, stream);
  if (e != hipSuccess) {
    (void)hipGetLastError();  // clear sticky error; deterministic fallback
    fb_p0<<<281, 512, 0, stream>>>(node, idxw, Wemb, bemb, W1, W2, dis, bvec,
                                   TWc, TW2);
    fb_p1<<<768, 512, 0, stream>>>(node, W3, TWc, bvec, TW3, xA);
    fb_agg<true, false><<<1024, 512, 0, stream>>>(xA, idxw, dis, b1, node, xO);
    fb_gemm<<<512, 512, 0, stream>>>(xO, TW2, xA);
    fb_agg<true, false><<<1024, 512, 0, stream>>>(xA, idxw, dis, b2, node, xO);
    fb_gemm<<<512, 512, 0, stream>>>(xO, TW3, xA);
    fb_agg<false, true><<<1024, 512, 0, stream>>>(xA, idxw, dis, b3, node, d_out);
  }
}

// Round 11
// 289.531 us; speedup vs baseline: 3.0114x; 3.0114x over previous
//
#include <hip/hip_runtime.h>
#include <stdint.h>

#define NN 8192
#define MM 16
#define FN 128
#define HH 512

typedef unsigned short u16;
typedef unsigned int u32;
typedef __bf16 bf16;
typedef __bf16 bf16x8 __attribute__((ext_vector_type(8)));
typedef float f32x4 __attribute__((ext_vector_type(4)));

// async global->LDS, 16B/lane; LDS dest = wave-uniform base + lane*16
__device__ __forceinline__ void gld_lds16(const u16* g, u16* l) {
  __builtin_amdgcn_global_load_lds(
      (const __attribute__((address_space(1))) void*)g,
      (__attribute__((address_space(3))) void*)l, 16, 0, 0);
}

// ---- dtype probes (per-wave; ~2 cached loads + ballot) ----
__device__ __forceinline__ int probe_f32(const u16* w) {
  int lane = threadIdx.x & 63;
  int e = (w[2 * lane] >> 7) & 0xFF;
  unsigned long long m = __ballot(!(e == 0 || (e >= 90 && e <= 140)));
  return __popcll(m) >= 8;
}
__device__ __forceinline__ int probe_i64(const u32* w) {
  int lane = threadIdx.x & 63;
  unsigned long long m = __ballot(lane < 32 && w[2 * lane + 1] != 0);
  return m == 0;
}
__device__ __forceinline__ bf16 cvt_elem(const void* p, size_t i, int f32) {
  return f32 ? (bf16)((const float*)p)[i] : ((const bf16*)p)[i];
}

// ---- transpose one 32x32 tile of W (512 x 512) -> T (512 x 512), 256 thr ----
__device__ __forceinline__ void transpose_tile(const void* __restrict__ W,
                                               u16* __restrict__ T, int tt,
                                               int f32in, u16* sm) {
  const int k0 = (tt >> 4) * 32, n0 = (tt & 15) * 32;
  const int tx = threadIdx.x & 31, ty = threadIdx.x >> 5;  // ty 0..7
#pragma unroll
  for (int r = ty; r < 32; r += 8) {
    bf16 v = cvt_elem(W, (size_t)(k0 + r) * HH + n0 + tx, f32in);
    sm[r * 33 + tx] = *(u16*)&v;
  }
  __syncthreads();
#pragma unroll
  for (int r = ty; r < 32; r += 8)
    T[(size_t)(n0 + r) * HH + k0 + tx] = sm[tx * 33 + r];
}

// ---- GEMM tile: C[rtile*64..+64][ctile*128..+128] = A @ Bt^T (+ biasf)
// 256 thr / 4 waves (2x2), wave 32x64 (2x4 accs of 16x16x32), BK=64,
// gld_lds + XOR swizzle (LDS chunk (row,cc) holds k-chunk gc = cc^(row&7)).
// R5-R9-verified: correct, 0 bank conflicts. Writes bf16, row stride cstride.
__device__ __forceinline__ void gemm_tile(const void* __restrict__ A, int K,
                                          int af32, const u16* __restrict__ Bt,
                                          const float* __restrict__ biasf,
                                          int rtile, int ctile,
                                          u16* __restrict__ C, int cstride,
                                          u16* As, u16* Bs) {
  const int tid = threadIdx.x;
  const int wave = tid >> 6, lane = tid & 63;
  const int wr = wave >> 1, wc = wave & 1;
  const int quad = lane >> 4, l16 = lane & 15;
  f32x4 acc[2][4] = {};

  int arow[2], agc[2], brow[4], bgc[4];
#pragma unroll
  for (int i = 0; i < 2; ++i) {
    int c = i * 256 + tid;
    arow[i] = c >> 3;
    agc[i] = (c & 7) ^ (arow[i] & 7);
  }
#pragma unroll
  for (int i = 0; i < 4; ++i) {
    int c = i * 256 + tid;
    brow[i] = c >> 3;
    bgc[i] = (c & 7) ^ (brow[i] & 7);
  }
  u16* AsW = As + wave * 512;  // wave-uniform LDS bases (chunk c -> c*16 B)
  u16* BsW = Bs + wave * 512;

  for (int k0 = 0; k0 < K; k0 += 64) {
    __syncthreads();  // prev iter's ds_reads done
    if (af32) {
      const float* Af = (const float*)A;
      bf16x8 v[2];
#pragma unroll
      for (int i = 0; i < 2; ++i) {
        const float* p = &Af[(size_t)(rtile * 64 + arow[i]) * K + k0 + agc[i] * 8];
        f32x4 x0 = *(const f32x4*)p, x1 = *(const f32x4*)(p + 4);
#pragma unroll
        for (int t = 0; t < 4; ++t) {
          v[i][t] = (bf16)x0[t];
          v[i][4 + t] = (bf16)x1[t];
        }
      }
#pragma unroll
      for (int i = 0; i < 2; ++i) *(bf16x8*)&As[(i * 256 + tid) * 8] = v[i];
    } else {
      const u16* Ab = (const u16*)A;
#pragma unroll
      for (int i = 0; i < 2; ++i)
        gld_lds16(&Ab[(size_t)(rtile * 64 + arow[i]) * K + k0 + agc[i] * 8],
                  AsW + i * 2048);
    }
#pragma unroll
    for (int i = 0; i < 4; ++i)
      gld_lds16(&Bt[(size_t)(ctile * 128 + brow[i]) * K + k0 + bgc[i] * 8],
                BsW + i * 2048);
    __syncthreads();  // drains vmcnt (DMA complete)
#pragma unroll
    for (int h = 0; h < 2; ++h) {
      bf16x8 af[2], bfr[4];
#pragma unroll
      for (int i = 0; i < 2; ++i) {
        int r = wr * 32 + i * 16 + l16;
        int cc = (h * 4 + quad) ^ (r & 7);
        af[i] = *(const bf16x8*)&As[r * 64 + cc * 8];
      }
#pragma unroll
      for (int j = 0; j < 4; ++j) {
        int n = wc * 64 + j * 16 + l16;
        int cc = (h * 4 + quad) ^ (n & 7);
        bfr[j] = *(const bf16x8*)&Bs[n * 64 + cc * 8];
      }
#pragma unroll
      for (int i = 0; i < 2; ++i)
#pragma unroll
        for (int j = 0; j < 4; ++j)
          acc[i][j] = __builtin_amdgcn_mfma_f32_16x16x32_bf16(af[i], bfr[j],
                                                              acc[i][j], 0, 0, 0);
    }
  }

  // C/D layout: col = lane&15, row = quad*4 + reg (m89/m91)
  const int crow0 = rtile * 64 + wr * 32 + quad * 4;
  const int ccol0 = ctile * 128 + wc * 64 + l16;
#pragma unroll
  for (int j = 0; j < 4; ++j) {
    const int col = ccol0 + j * 16;
    const float bv = biasf ? biasf[col] : 0.f;
#pragma unroll
    for (int i = 0; i < 2; ++i)
#pragma unroll
      for (int r = 0; r < 4; ++r) {
        bf16 o = (bf16)(acc[i][j][r] + bv);
        C[(size_t)(crow0 + i * 16 + r) * cstride + col] = *(u16*)&o;
      }
  }
}

// ---- TWc tile (vb 0..7): TWc = (Wemb@W1)^T from RAW inputs (no TW1 needed).
// Same fragment math as gemm_tile; B staged by in-LDS transpose of raw W1
// rows (R10-verified scatter: Bs[n*64 + ((kk>>3)^(n&7))*8 + (kk&7)]);
// C written transposed into TWc (512 x 128).
__device__ void wc_tile(int vb, const void* __restrict__ Wemb,
                        const void* __restrict__ W1, int f32in,
                        u16* __restrict__ TWc, u16* As, u16* Bs) {
  const int tid = threadIdx.x;
  const int rtile = vb >> 2, ctile = vb & 3;
  const int wave = tid >> 6, lane = tid & 63;
  const int wr = wave >> 1, wc = wave & 1;
  const int quad = lane >> 4, l16 = lane & 15;
  f32x4 acc[2][4] = {};
  int arow[2], agc[2];
#pragma unroll
  for (int i = 0; i < 2; ++i) {
    int c = i * 256 + tid;
    arow[i] = c >> 3;
    agc[i] = (c & 7) ^ (arow[i] & 7);
  }
  for (int k0 = 0; k0 < HH; k0 += 64) {
    __syncthreads();
#pragma unroll
    for (int i = 0; i < 2; ++i) {  // A: Wemb rows, linear swizzled chunks
      size_t src = (size_t)(rtile * 64 + arow[i]) * HH + k0 + agc[i] * 8;
      bf16x8 av;
      if (f32in) {
        const float* pp = (const float*)Wemb + src;
        f32x4 x0 = *(const f32x4*)pp, x1 = *(const f32x4*)(pp + 4);
#pragma unroll
        for (int t = 0; t < 4; ++t) { av[t] = (bf16)x0[t]; av[4 + t] = (bf16)x1[t]; }
      } else {
        av = *(const bf16x8*)((const u16*)Wemb + src);
      }
      *(bf16x8*)&As[(i * 256 + tid) * 8] = av;
    }
#pragma unroll
    for (int i = 0; i < 4; ++i) {  // B: W1 rows -> transposed swizzled LDS
      int t2 = i * 256 + tid;      // 0..1023
      int kk = t2 >> 4, seg = (t2 & 15) * 8;
      size_t src = (size_t)(k0 + kk) * HH + ctile * 128 + seg;
      bf16 e8[8];
      if (f32in) {
        const float* pp = (const float*)W1 + src;
        f32x4 x0 = *(const f32x4*)pp, x1 = *(const f32x4*)(pp + 4);
#pragma unroll
        for (int t = 0; t < 4; ++t) { e8[t] = (bf16)x0[t]; e8[4 + t] = (bf16)x1[t]; }
      } else {
        bf16x8 v = *(const bf16x8*)((const u16*)W1 + src);
#pragma unroll
        for (int t = 0; t < 8; ++t) e8[t] = v[t];
      }
#pragma unroll
      for (int j = 0; j < 8; ++j) {
        int n = seg + j;
        int cc = (kk >> 3) ^ j;  // j == n&7
        Bs[n * 64 + cc * 8 + (kk & 7)] = *(u16*)&e8[j];
      }
    }
    __syncthreads();
#pragma unroll
    for (int h = 0; h < 2; ++h) {
      bf16x8 af[2], bfr[4];
#pragma unroll
      for (int i = 0; i < 2; ++i) {
        int r = wr * 32 + i * 16 + l16;
        int cc = (h * 4 + quad) ^ (r & 7);
        af[i] = *(const bf16x8*)&As[r * 64 + cc * 8];
      }
#pragma unroll
      for (int j = 0; j < 4; ++j) {
        int n = wc * 64 + j * 16 + l16;
        int cc = (h * 4 + quad) ^ (n & 7);
        bfr[j] = *(const bf16x8*)&Bs[n * 64 + cc * 8];
      }
#pragma unroll
      for (int i = 0; i < 2; ++i)
#pragma unroll
        for (int j = 0; j < 4; ++j)
          acc[i][j] = __builtin_amdgcn_mfma_f32_16x16x32_bf16(af[i], bfr[j],
                                                              acc[i][j], 0, 0, 0);
    }
  }
  const int crow0 = rtile * 64 + wr * 32 + quad * 4;  // Wemb row = TWc col
  const int ccol0 = ctile * 128 + wc * 64 + l16;      // W1 col  = TWc row
#pragma unroll
  for (int j = 0; j < 4; ++j)
#pragma unroll
    for (int i = 0; i < 2; ++i)
#pragma unroll
      for (int r = 0; r < 4; ++r) {
        bf16 o = (bf16)acc[i][j][r];
        TWc[(size_t)(ccol0 + j * 16) * FN + crow0 + i * 16 + r] = *(u16*)&o;
      }
}

// ---- prep (ONE launch): TW2 transposes (0..255) + deg (256..287) +
//      TWc direct (288..295) + bvec (296..297)
__global__ __launch_bounds__(256) void prep_kernel(
    const u16* __restrict__ node, const u32* __restrict__ idxw,
    const void* __restrict__ Wemb, const void* __restrict__ bemb,
    const void* __restrict__ W1, const void* __restrict__ W2,
    float* __restrict__ dis, float* __restrict__ bvec, u16* __restrict__ TWc,
    u16* __restrict__ TW2) {
  __shared__ __align__(16) u16 smem[12288];  // 24 KB
  const int bid = blockIdx.x, tid = threadIdx.x;
  const int f32in = probe_f32(node);
  if (bid < 256) {
    transpose_tile(W2, TW2, bid, f32in, smem);
  } else if (bid < 288) {
    const int i64 = probe_i64(idxw);
    const int* idx = (const int*)idxw;
    const int i = (bid - 256) * 256 + tid;
    int c = 1;
#pragma unroll
    for (int e = 0; e < MM; ++e) c += (idx[(i * MM + e) << i64] >= 0) ? 1 : 0;
    dis[i] = rsqrtf((float)c);
  } else if (bid < 296) {
    wc_tile(bid - 288, Wemb, W1, f32in, TWc, smem, smem + 4096);
  } else {
    // bvec[n] = sum_m bemb[m] * W1[m][n]
    float* bembS = (float*)smem;
    bembS[tid] = (float)cvt_elem(bemb, tid, f32in);
    bembS[256 + tid] = (float)cvt_elem(bemb, 256 + tid, f32in);
    __syncthreads();
    const int n = (bid - 296) * 256 + tid;
    float acc = 0.f;
#pragma unroll 8
    for (int m = 0; m < HH; ++m)
      acc += bembS[m] * (float)cvt_elem(W1, (size_t)m * HH + n, f32in);
    bvec[n] = acc;
  }
}

// ---- G1: t = node @ TWc^T + bvec (blocks 0..511, K=128, A maybe fp32)
//      + TW3 transposes (blocks 512..767) riding on idle CUs
__global__ __launch_bounds__(256) void g1_kernel(const u16* __restrict__ node,
                                                 const void* __restrict__ W3,
                                                 const u16* __restrict__ TWc,
                                                 const float* __restrict__ bvec,
                                                 u16* __restrict__ TW3,
                                                 u16* __restrict__ C) {
  __shared__ __align__(16) u16 smem[12288];
  const int bid = blockIdx.x;
  const int f32in = probe_f32(node);
  if (bid < 512) {
    gemm_tile(node, FN, f32in, TWc, bvec, bid >> 2, bid & 3, C, HH, smem,
              smem + 4096);
  } else {
    transpose_tile(W3, TW3, bid - 512, f32in, smem);
  }
}

// ---- mid GEMM: t = x @ W^T (no epilogue; bias/relu live in the next agg)
__global__ __launch_bounds__(256) void gemm_mid(const u16* __restrict__ A,
                                                const u16* __restrict__ Bt,
                                                u16* __restrict__ C) {
  __shared__ __align__(16) u16 smem[12288];
  gemm_tile(A, HH, 0, Bt, nullptr, blockIdx.x, blockIdx.y, C, HH, smem,
            smem + 4096);
}

// ---- agg + epilogue: y[i,:] = act( d[i]*( d[i]*t[i,:] + sum d[j]*t[j,:] ) + b )
// XCD-pinned column strips (R7): strip s read only by blocks with
// blockIdx%8 in {2s,2s+1} -> 2 MB of t resident per XCD-pair L2.
template <bool RELU, bool FINAL>
__global__ __launch_bounds__(256) void agg_kernel(
    const u16* __restrict__ t, const u32* __restrict__ idxw,
    const float* __restrict__ dis, const void* __restrict__ bias,
    const u16* __restrict__ nodeprobe, void* __restrict__ y) {
  const int i64 = probe_i64(idxw);
  const int f32io = probe_f32(nodeprobe);
  const int* idx = (const int*)idxw;
  const int b = blockIdx.x;
  const int strip = (b & 7) >> 1;          // 0..3, pinned to XCD pair
  const int grp = (b >> 3) * 2 + (b & 1);  // 0..511 node group
  const int wave = threadIdx.x >> 6, lane = threadIdx.x & 63;
  const int node = grp * 16 + wave * 4 + (lane >> 4);
  const int c0 = strip * 128 + (lane & 15) * 8;
  const float wi = dis[node];
  float acc[8];
  bf16x8 xs = *(const bf16x8*)&t[(size_t)node * HH + c0];
#pragma unroll
  for (int k = 0; k < 8; ++k) acc[k] = wi * wi * (float)xs[k];
#pragma unroll
  for (int e = 0; e < MM; ++e) {
    const int j = idx[(node * MM + e) << i64];
    if (j >= 0) {
      const float w = wi * dis[j];
      bf16x8 v = *(const bf16x8*)&t[(size_t)j * HH + c0];
#pragma unroll
      for (int k = 0; k < 8; ++k) acc[k] += w * (float)v[k];
    }
  }
  float bv[8];
  if (f32io) {
    f32x4 b0 = *(const f32x4*)&((const float*)bias)[c0];
    f32x4 b1 = *(const f32x4*)&((const float*)bias)[c0 + 4];
#pragma unroll
    for (int k = 0; k < 4; ++k) { bv[k] = b0[k]; bv[4 + k] = b1[k]; }
  } else {
    bf16x8 bb = *(const bf16x8*)&((const u16*)bias)[c0];
#pragma unroll
    for (int k = 0; k < 8; ++k) bv[k] = (float)bb[k];
  }
#pragma unroll
  for (int k = 0; k < 8; ++k) {
    acc[k] += bv[k];
    if (RELU) acc[k] = fmaxf(acc[k], 0.f);
  }
  if (FINAL && f32io) {
    float* O = (float*)y;
    f32x4 o0, o1;
#pragma unroll
    for (int k = 0; k < 4; ++k) { o0[k] = acc[k]; o1[k] = acc[4 + k]; }
    *(f32x4*)&O[(size_t)node * HH + c0] = o0;
    *(f32x4*)&O[(size_t)node * HH + c0 + 4] = o1;
  } else {
    bf16x8 o;
#pragma unroll
    for (int k = 0; k < 8; ++k) o[k] = (bf16)acc[k];
    *(bf16x8*)&((u16*)y)[(size_t)node * HH + c0] = o;
  }
}

extern "C" void kernel_launch(void* const* d_in, const int* in_sizes, int n_in,
                              void* d_out, int out_size, void* d_ws, size_t ws_size,
                              hipStream_t stream) {
  const u16* node = (const u16*)d_in[0];
  const u32* idxw = (const u32*)d_in[1];
  const void* Wemb = d_in[2];
  const void* bemb = d_in[3];
  const void* W1 = d_in[4];
  const void* b1 = d_in[5];
  const void* W2 = d_in[6];
  const void* b2 = d_in[7];
  const void* W3 = d_in[8];
  const void* b3 = d_in[9];

  char* p = (char*)d_ws;
  float* dis = (float*)p;   p += NN * sizeof(float);
  float* bvec = (float*)p;  p += HH * sizeof(float);
  u16* TWc = (u16*)p;       p += (size_t)HH * FN * 2;
  u16* TW2 = (u16*)p;       p += (size_t)HH * HH * 2;
  u16* TW3 = (u16*)p;       p += (size_t)HH * HH * 2;
  u16* xA = (u16*)p;        // 8 MB GEMM-out buffer
  u16* xO = (u16*)d_out;    // d_out doubles as bf16 ping buffer

  prep_kernel<<<298, 256, 0, stream>>>(node, idxw, Wemb, bemb, W1, W2, dis,
                                       bvec, TWc, TW2);
  g1_kernel<<<768, 256, 0, stream>>>(node, W3, TWc, bvec, TW3, xA);
  agg_kernel<true, false>
      <<<NN / 4, 256, 0, stream>>>(xA, idxw, dis, b1, node, xO);
  gemm_mid<<<dim3(128, 4), 256, 0, stream>>>(xO, TW2, xA);
  agg_kernel<true, false>
      <<<NN / 4, 256, 0, stream>>>(xA, idxw, dis, b2, node, xO);
  gemm_mid<<<dim3(128, 4), 256, 0, stream>>>(xO, TW3, xA);
  agg_kernel<false, true>
      <<<NN / 4, 256, 0, stream>>>(xA, idxw, dis, b3, node, d_out);
}

// Round 12
// 179.383 us; speedup vs baseline: 4.8606x; 1.6140x over previous
//
#include <hip/hip_runtime.h>
#include <stdint.h>

#define NN 8192
#define MM 16
#define FN 128
#define HH 512

typedef unsigned short u16;
typedef unsigned int u32;
typedef __bf16 bf16;
typedef __bf16 bf16x8 __attribute__((ext_vector_type(8)));
typedef float f32x4 __attribute__((ext_vector_type(4)));

// async global->LDS, 16B/lane; LDS dest = wave-uniform base + lane*16
__device__ __forceinline__ void gld_lds16(const u16* g, u16* l) {
  __builtin_amdgcn_global_load_lds(
      (const __attribute__((address_space(1))) void*)g,
      (__attribute__((address_space(3))) void*)l, 16, 0, 0);
}

// ---- dtype probes (per-wave; ~2 cached loads + ballot) ----
__device__ __forceinline__ int probe_f32(const u16* w) {
  int lane = threadIdx.x & 63;
  int e = (w[2 * lane] >> 7) & 0xFF;
  unsigned long long m = __ballot(!(e == 0 || (e >= 90 && e <= 140)));
  return __popcll(m) >= 8;
}
__device__ __forceinline__ int probe_i64(const u32* w) {
  int lane = threadIdx.x & 63;
  unsigned long long m = __ballot(lane < 32 && w[2 * lane + 1] != 0);
  return m == 0;
}
__device__ __forceinline__ bf16 cvt_elem(const void* p, size_t i, int f32) {
  return f32 ? (bf16)((const float*)p)[i] : ((const bf16*)p)[i];
}

// ---- transpose one 32x32 tile of W (512 x 512) -> T (512 x 512), 256 thr ----
__device__ __forceinline__ void transpose_tile(const void* __restrict__ W,
                                               u16* __restrict__ T, int tt,
                                               int f32in, u16* sm) {
  const int k0 = (tt >> 4) * 32, n0 = (tt & 15) * 32;
  const int tx = threadIdx.x & 31, ty = threadIdx.x >> 5;  // ty 0..7
#pragma unroll
  for (int r = ty; r < 32; r += 8) {
    bf16 v = cvt_elem(W, (size_t)(k0 + r) * HH + n0 + tx, f32in);
    sm[r * 33 + tx] = *(u16*)&v;
  }
  __syncthreads();
#pragma unroll
  for (int r = ty; r < 32; r += 8)
    T[(size_t)(n0 + r) * HH + k0 + tx] = sm[tx * 33 + r];
}

// ---- GEMM tile: C[rtile*64..+64][ctile*128..+128] = A @ Bt^T (+ biasf)
// 256 thr / 4 waves (2x2), wave 32x64 (2x4 accs of 16x16x32), BK=64,
// gld_lds + XOR swizzle (LDS chunk (row,cc) holds k-chunk gc = cc^(row&7)).
// R5-R11-verified: correct, 0 bank conflicts. Writes bf16, row stride cstride.
__device__ __forceinline__ void gemm_tile(const void* __restrict__ A, int K,
                                          int af32, const u16* __restrict__ Bt,
                                          const float* __restrict__ biasf,
                                          int rtile, int ctile,
                                          u16* __restrict__ C, int cstride,
                                          u16* As, u16* Bs) {
  const int tid = threadIdx.x;
  const int wave = tid >> 6, lane = tid & 63;
  const int wr = wave >> 1, wc = wave & 1;
  const int quad = lane >> 4, l16 = lane & 15;
  f32x4 acc[2][4] = {};

  int arow[2], agc[2], brow[4], bgc[4];
#pragma unroll
  for (int i = 0; i < 2; ++i) {
    int c = i * 256 + tid;
    arow[i] = c >> 3;
    agc[i] = (c & 7) ^ (arow[i] & 7);
  }
#pragma unroll
  for (int i = 0; i < 4; ++i) {
    int c = i * 256 + tid;
    brow[i] = c >> 3;
    bgc[i] = (c & 7) ^ (brow[i] & 7);
  }
  u16* AsW = As + wave * 512;  // wave-uniform LDS bases (chunk c -> c*16 B)
  u16* BsW = Bs + wave * 512;

  for (int k0 = 0; k0 < K; k0 += 64) {
    __syncthreads();  // prev iter's ds_reads done
    if (af32) {
      const float* Af = (const float*)A;
      bf16x8 v[2];
#pragma unroll
      for (int i = 0; i < 2; ++i) {
        const float* p = &Af[(size_t)(rtile * 64 + arow[i]) * K + k0 + agc[i] * 8];
        f32x4 x0 = *(const f32x4*)p, x1 = *(const f32x4*)(p + 4);
#pragma unroll
        for (int t = 0; t < 4; ++t) {
          v[i][t] = (bf16)x0[t];
          v[i][4 + t] = (bf16)x1[t];
        }
      }
#pragma unroll
      for (int i = 0; i < 2; ++i) *(bf16x8*)&As[(i * 256 + tid) * 8] = v[i];
    } else {
      const u16* Ab = (const u16*)A;
#pragma unroll
      for (int i = 0; i < 2; ++i)
        gld_lds16(&Ab[(size_t)(rtile * 64 + arow[i]) * K + k0 + agc[i] * 8],
                  AsW + i * 2048);
    }
#pragma unroll
    for (int i = 0; i < 4; ++i)
      gld_lds16(&Bt[(size_t)(ctile * 128 + brow[i]) * K + k0 + bgc[i] * 8],
                BsW + i * 2048);
    __syncthreads();  // drains vmcnt (DMA complete)
#pragma unroll
    for (int h = 0; h < 2; ++h) {
      bf16x8 af[2], bfr[4];
#pragma unroll
      for (int i = 0; i < 2; ++i) {
        int r = wr * 32 + i * 16 + l16;
        int cc = (h * 4 + quad) ^ (r & 7);
        af[i] = *(const bf16x8*)&As[r * 64 + cc * 8];
      }
#pragma unroll
      for (int j = 0; j < 4; ++j) {
        int n = wc * 64 + j * 16 + l16;
        int cc = (h * 4 + quad) ^ (n & 7);
        bfr[j] = *(const bf16x8*)&Bs[n * 64 + cc * 8];
      }
#pragma unroll
      for (int i = 0; i < 2; ++i)
#pragma unroll
        for (int j = 0; j < 4; ++j)
          acc[i][j] = __builtin_amdgcn_mfma_f32_16x16x32_bf16(af[i], bfr[j],
                                                              acc[i][j], 0, 0, 0);
    }
  }

  // C/D layout: col = lane&15, row = quad*4 + reg (m89/m91)
  const int crow0 = rtile * 64 + wr * 32 + quad * 4;
  const int ccol0 = ctile * 128 + wc * 64 + l16;
#pragma unroll
  for (int j = 0; j < 4; ++j) {
    const int col = ccol0 + j * 16;
    const float bv = biasf ? biasf[col] : 0.f;
#pragma unroll
    for (int i = 0; i < 2; ++i)
#pragma unroll
      for (int r = 0; r < 4; ++r) {
        bf16 o = (bf16)(acc[i][j][r] + bv);
        C[(size_t)(crow0 + i * 16 + r) * cstride + col] = *(u16*)&o;
      }
  }
}

// ---- TWc tile (vb 0..7): TWc = (Wemb@W1)^T from RAW inputs (no TW1 needed).
// Same fragment math as gemm_tile; B staged by in-LDS transpose of raw W1
// rows (R10/R11-verified scatter); C written transposed into TWc (512 x 128).
__device__ void wc_tile(int vb, const void* __restrict__ Wemb,
                        const void* __restrict__ W1, int f32in,
                        u16* __restrict__ TWc, u16* As, u16* Bs) {
  const int tid = threadIdx.x;
  const int rtile = vb >> 2, ctile = vb & 3;
  const int wave = tid >> 6, lane = tid & 63;
  const int wr = wave >> 1, wc = wave & 1;
  const int quad = lane >> 4, l16 = lane & 15;
  f32x4 acc[2][4] = {};
  int arow[2], agc[2];
#pragma unroll
  for (int i = 0; i < 2; ++i) {
    int c = i * 256 + tid;
    arow[i] = c >> 3;
    agc[i] = (c & 7) ^ (arow[i] & 7);
  }
  for (int k0 = 0; k0 < HH; k0 += 64) {
    __syncthreads();
#pragma unroll
    for (int i = 0; i < 2; ++i) {  // A: Wemb rows, linear swizzled chunks
      size_t src = (size_t)(rtile * 64 + arow[i]) * HH + k0 + agc[i] * 8;
      bf16x8 av;
      if (f32in) {
        const float* pp = (const float*)Wemb + src;
        f32x4 x0 = *(const f32x4*)pp, x1 = *(const f32x4*)(pp + 4);
#pragma unroll
        for (int t = 0; t < 4; ++t) { av[t] = (bf16)x0[t]; av[4 + t] = (bf16)x1[t]; }
      } else {
        av = *(const bf16x8*)((const u16*)Wemb + src);
      }
      *(bf16x8*)&As[(i * 256 + tid) * 8] = av;
    }
#pragma unroll
    for (int i = 0; i < 4; ++i) {  // B: W1 rows -> transposed swizzled LDS
      int t2 = i * 256 + tid;      // 0..1023
      int kk = t2 >> 4, seg = (t2 & 15) * 8;
      size_t src = (size_t)(k0 + kk) * HH + ctile * 128 + seg;
      bf16 e8[8];
      if (f32in) {
        const float* pp = (const float*)W1 + src;
        f32x4 x0 = *(const f32x4*)pp, x1 = *(const f32x4*)(pp + 4);
#pragma unroll
        for (int t = 0; t < 4; ++t) { e8[t] = (bf16)x0[t]; e8[4 + t] = (bf16)x1[t]; }
      } else {
        bf16x8 v = *(const bf16x8*)((const u16*)W1 + src);
#pragma unroll
        for (int t = 0; t < 8; ++t) e8[t] = v[t];
      }
#pragma unroll
      for (int j = 0; j < 8; ++j) {
        int n = seg + j;
        int cc = (kk >> 3) ^ j;  // j == n&7
        Bs[n * 64 + cc * 8 + (kk & 7)] = *(u16*)&e8[j];
      }
    }
    __syncthreads();
#pragma unroll
    for (int h = 0; h < 2; ++h) {
      bf16x8 af[2], bfr[4];
#pragma unroll
      for (int i = 0; i < 2; ++i) {
        int r = wr * 32 + i * 16 + l16;
        int cc = (h * 4 + quad) ^ (r & 7);
        af[i] = *(const bf16x8*)&As[r * 64 + cc * 8];
      }
#pragma unroll
      for (int j = 0; j < 4; ++j) {
        int n = wc * 64 + j * 16 + l16;
        int cc = (h * 4 + quad) ^ (n & 7);
        bfr[j] = *(const bf16x8*)&Bs[n * 64 + cc * 8];
      }
#pragma unroll
      for (int i = 0; i < 2; ++i)
#pragma unroll
        for (int j = 0; j < 4; ++j)
          acc[i][j] = __builtin_amdgcn_mfma_f32_16x16x32_bf16(af[i], bfr[j],
                                                              acc[i][j], 0, 0, 0);
    }
  }
  const int crow0 = rtile * 64 + wr * 32 + quad * 4;  // Wemb row = TWc col
  const int ccol0 = ctile * 128 + wc * 64 + l16;      // W1 col  = TWc row
#pragma unroll
  for (int j = 0; j < 4; ++j)
#pragma unroll
    for (int i = 0; i < 2; ++i)
#pragma unroll
      for (int r = 0; r < 4; ++r) {
        bf16 o = (bf16)acc[i][j][r];
        TWc[(size_t)(ccol0 + j * 16) * FN + crow0 + i * 16 + r] = *(u16*)&o;
      }
}

// ---- prep (ONE launch): TW2 transposes (0..255) + deg (256..287) +
//      TWc direct (288..295) + bvec (296..297)
__global__ __launch_bounds__(256) void prep_kernel(
    const u16* __restrict__ node, const u32* __restrict__ idxw,
    const void* __restrict__ Wemb, const void* __restrict__ bemb,
    const void* __restrict__ W1, const void* __restrict__ W2,
    float* __restrict__ dis, float* __restrict__ bvec, u16* __restrict__ TWc,
    u16* __restrict__ TW2) {
  __shared__ __align__(16) u16 smem[12288];  // 24 KB
  const int bid = blockIdx.x, tid = threadIdx.x;
  const int f32in = probe_f32(node);
  if (bid < 256) {
    transpose_tile(W2, TW2, bid, f32in, smem);
  } else if (bid < 288) {
    const int i64 = probe_i64(idxw);
    const int* idx = (const int*)idxw;
    const int i = (bid - 256) * 256 + tid;
    int c = 1;
#pragma unroll
    for (int e = 0; e < MM; ++e) c += (idx[(i * MM + e) << i64] >= 0) ? 1 : 0;
    dis[i] = rsqrtf((float)c);
  } else if (bid < 296) {
    wc_tile(bid - 288, Wemb, W1, f32in, TWc, smem, smem + 4096);
  } else {
    // bvec[n] = sum_m bemb[m] * W1[m][n].
    // Dtype branch HOISTED out of the loop (R11 bug: per-element runtime
    // ternary -> branch per iter -> no load batching -> 141 us serial tail).
    float* bembS = (float*)smem;
    bembS[tid] = (float)cvt_elem(bemb, tid, f32in);
    bembS[256 + tid] = (float)cvt_elem(bemb, 256 + tid, f32in);
    __syncthreads();
    const int n = (bid - 296) * 256 + tid;
    float acc = 0.f;
    if (f32in) {
      const float* W1f = (const float*)W1;
#pragma unroll 16
      for (int m = 0; m < HH; ++m) acc += bembS[m] * W1f[(size_t)m * HH + n];
    } else {
      const u16* W1b = (const u16*)W1;
#pragma unroll 16
      for (int m = 0; m < HH; ++m)
        acc += bembS[m] * (float)(*(const bf16*)&W1b[(size_t)m * HH + n]);
    }
    bvec[n] = acc;
  }
}

// ---- G1: t = node @ TWc^T + bvec (blocks 0..511, K=128, A maybe fp32)
//      + TW3 transposes (blocks 512..767) riding on idle CUs
__global__ __launch_bounds__(256) void g1_kernel(const u16* __restrict__ node,
                                                 const void* __restrict__ W3,
                                                 const u16* __restrict__ TWc,
                                                 const float* __restrict__ bvec,
                                                 u16* __restrict__ TW3,
                                                 u16* __restrict__ C) {
  __shared__ __align__(16) u16 smem[12288];
  const int bid = blockIdx.x;
  const int f32in = probe_f32(node);
  if (bid < 512) {
    gemm_tile(node, FN, f32in, TWc, bvec, bid >> 2, bid & 3, C, HH, smem,
              smem + 4096);
  } else {
    transpose_tile(W3, TW3, bid - 512, f32in, smem);
  }
}

// ---- mid GEMM: t = x @ W^T (no epilogue; bias/relu live in the next agg)
__global__ __launch_bounds__(256) void gemm_mid(const u16* __restrict__ A,
                                                const u16* __restrict__ Bt,
                                                u16* __restrict__ C) {
  __shared__ __align__(16) u16 smem[12288];
  gemm_tile(A, HH, 0, Bt, nullptr, blockIdx.x, blockIdx.y, C, HH, smem,
            smem + 4096);
}

// ---- agg + epilogue: y[i,:] = act( d[i]*( d[i]*t[i,:] + sum d[j]*t[j,:] ) + b )
// XCD-pinned column strips (R7): strip s read only by blocks with
// blockIdx%8 in {2s,2s+1} -> 2 MB of t resident per XCD-pair L2.
template <bool RELU, bool FINAL>
__global__ __launch_bounds__(256) void agg_kernel(
    const u16* __restrict__ t, const u32* __restrict__ idxw,
    const float* __restrict__ dis, const void* __restrict__ bias,
    const u16* __restrict__ nodeprobe, void* __restrict__ y) {
  const int i64 = probe_i64(idxw);
  const int f32io = probe_f32(nodeprobe);
  const int* idx = (const int*)idxw;
  const int b = blockIdx.x;
  const int strip = (b & 7) >> 1;          // 0..3, pinned to XCD pair
  const int grp = (b >> 3) * 2 + (b & 1);  // 0..511 node group
  const int wave = threadIdx.x >> 6, lane = threadIdx.x & 63;
  const int node = grp * 16 + wave * 4 + (lane >> 4);
  const int c0 = strip * 128 + (lane & 15) * 8;
  const float wi = dis[node];
  float acc[8];
  bf16x8 xs = *(const bf16x8*)&t[(size_t)node * HH + c0];
#pragma unroll
  for (int k = 0; k < 8; ++k) acc[k] = wi * wi * (float)xs[k];
#pragma unroll
  for (int e = 0; e < MM; ++e) {
    const int j = idx[(node * MM + e) << i64];
    if (j >= 0) {
      const float w = wi * dis[j];
      bf16x8 v = *(const bf16x8*)&t[(size_t)j * HH + c0];
#pragma unroll
      for (int k = 0; k < 8; ++k) acc[k] += w * (float)v[k];
    }
  }
  float bv[8];
  if (f32io) {
    f32x4 b0 = *(const f32x4*)&((const float*)bias)[c0];
    f32x4 b1 = *(const f32x4*)&((const float*)bias)[c0 + 4];
#pragma unroll
    for (int k = 0; k < 4; ++k) { bv[k] = b0[k]; bv[4 + k] = b1[k]; }
  } else {
    bf16x8 bb = *(const bf16x8*)&((const u16*)bias)[c0];
#pragma unroll
    for (int k = 0; k < 8; ++k) bv[k] = (float)bb[k];
  }
#pragma unroll
  for (int k = 0; k < 8; ++k) {
    acc[k] += bv[k];
    if (RELU) acc[k] = fmaxf(acc[k], 0.f);
  }
  if (FINAL && f32io) {
    float* O = (float*)y;
    f32x4 o0, o1;
#pragma unroll
    for (int k = 0; k < 4; ++k) { o0[k] = acc[k]; o1[k] = acc[4 + k]; }
    *(f32x4*)&O[(size_t)node * HH + c0] = o0;
    *(f32x4*)&O[(size_t)node * HH + c0 + 4] = o1;
  } else {
    bf16x8 o;
#pragma unroll
    for (int k = 0; k < 8; ++k) o[k] = (bf16)acc[k];
    *(bf16x8*)&((u16*)y)[(size_t)node * HH + c0] = o;
  }
}

extern "C" void kernel_launch(void* const* d_in, const int* in_sizes, int n_in,
                              void* d_out, int out_size, void* d_ws, size_t ws_size,
                              hipStream_t stream) {
  const u16* node = (const u16*)d_in[0];
  const u32* idxw = (const u32*)d_in[1];
  const void* Wemb = d_in[2];
  const void* bemb = d_in[3];
  const void* W1 = d_in[4];
  const void* b1 = d_in[5];
  const void* W2 = d_in[6];
  const void* b2 = d_in[7];
  const void* W3 = d_in[8];
  const void* b3 = d_in[9];

  char* p = (char*)d_ws;
  float* dis = (float*)p;   p += NN * sizeof(float);
  float* bvec = (float*)p;  p += HH * sizeof(float);
  u16* TWc = (u16*)p;       p += (size_t)HH * FN * 2;
  u16* TW2 = (u16*)p;       p += (size_t)HH * HH * 2;
  u16* TW3 = (u16*)p;       p += (size_t)HH * HH * 2;
  u16* xA = (u16*)p;        // 8 MB GEMM-out buffer
  u16* xO = (u16*)d_out;    // d_out doubles as bf16 ping buffer

  prep_kernel<<<298, 256, 0, stream>>>(node, idxw, Wemb, bemb, W1, W2, dis,
                                       bvec, TWc, TW2);
  g1_kernel<<<768, 256, 0, stream>>>(node, W3, TWc, bvec, TW3, xA);
  agg_kernel<true, false>
      <<<NN / 4, 256, 0, stream>>>(xA, idxw, dis, b1, node, xO);
  gemm_mid<<<dim3(128, 4), 256, 0, stream>>>(xO, TW2, xA);
  agg_kernel<true, false>
      <<<NN / 4, 256, 0, stream>>>(xA, idxw, dis, b2, node, xO);
  gemm_mid<<<dim3(128, 4), 256, 0, stream>>>(xO, TW3, xA);
  agg_kernel<false, true>
      <<<NN / 4, 256, 0, stream>>>(xA, idxw, dis, b3, node, d_out);
}